// Round 4
// baseline (19810.562 us; speedup 1.0000x reference)
//
#include <hip/hip_runtime.h>
#include <hip/hip_bf16.h>

#define B_ 32
#define T_ 2048
#define D_ 512
#define H_ 1024
#define G4_ 4096
#define NBLK 32    // recurrent blocks (1 per CU, co-resident)
#define JPB 32     // h-columns per recurrent block (H_/NBLK)
#define FSTRIDE 16 // flag padding: one flag per 64B line

typedef __attribute__((ext_vector_type(8))) short short8;
typedef __attribute__((ext_vector_type(4))) float f32x4;

__device__ __forceinline__ float sigmoidf_(float x) { return 1.0f / (1.0f + __expf(-x)); }
__device__ __forceinline__ float bf16bits_to_f(unsigned short u) {
  return __builtin_bit_cast(float, (unsigned int)u << 16);
}
__device__ __forceinline__ unsigned short f_to_bf16bits(float f) {
  __hip_bfloat16 h = __float2bfloat16(f);
  return __builtin_bit_cast(unsigned short, h);
}

// ---------------------------------------------------------------------------
// Precompute xg[row][col] = sum_k x[row][k] * W_ih[col][k]   (row = tloc*32+b)
// ---------------------------------------------------------------------------
__global__ __launch_bounds__(256) void xw_gemm(const float* __restrict__ x,
                                               const float* __restrict__ Wih,
                                               __hip_bfloat16* __restrict__ xg,
                                               int t0) {
  __shared__ __align__(16) __hip_bfloat16 As[128][40];
  __shared__ __align__(16) __hip_bfloat16 Bs[128][40];
  __shared__ __align__(16) __hip_bfloat16 Cs[128][132];

  const int tid = threadIdx.x;
  const int bx = blockIdx.x;           // N tile (0..31)
  const int by = blockIdx.y;           // M tile
  const int lane = tid & 63, wave = tid >> 6;
  const int wm = wave >> 1, wn = wave & 1;
  const int lr = lane & 15, kq = (lane >> 4) * 8;

  const int r  = tid >> 1, ks = (tid & 1) * 16;
  const int rowA = by * 128 + r;
  const int bb = rowA & 31, tg = t0 + (rowA >> 5);
  const float* aptr = x  + ((size_t)bb * T_ + tg) * D_ + ks;
  const float* bptr = Wih + (size_t)(bx * 128 + r) * D_ + ks;

  f32x4 acc[4][4];
#pragma unroll
  for (int i = 0; i < 4; ++i)
#pragma unroll
    for (int jj = 0; jj < 4; ++jj) acc[i][jj] = (f32x4){0.f, 0.f, 0.f, 0.f};

  for (int k0 = 0; k0 < D_; k0 += 32) {
    __hip_bfloat16 ta[16], tb[16];
#pragma unroll
    for (int q = 0; q < 4; ++q) {
      f32x4 va = ((const f32x4*)(aptr + k0))[q];
      f32x4 vb = ((const f32x4*)(bptr + k0))[q];
#pragma unroll
      for (int e = 0; e < 4; ++e) {
        ta[q * 4 + e] = __float2bfloat16(va[e]);
        tb[q * 4 + e] = __float2bfloat16(vb[e]);
      }
    }
    __syncthreads();  // protect previous iter's readers
    *(short8*)&As[r][ks]     = *(const short8*)&ta[0];
    *(short8*)&As[r][ks + 8] = *(const short8*)&ta[8];
    *(short8*)&Bs[r][ks]     = *(const short8*)&tb[0];
    *(short8*)&Bs[r][ks + 8] = *(const short8*)&tb[8];
    __syncthreads();

    short8 af[4], bf[4];
#pragma unroll
    for (int mi = 0; mi < 4; ++mi) af[mi] = *(const short8*)&As[wm * 64 + mi * 16 + lr][kq];
#pragma unroll
    for (int ni = 0; ni < 4; ++ni) bf[ni] = *(const short8*)&Bs[wn * 64 + ni * 16 + lr][kq];
#pragma unroll
    for (int mi = 0; mi < 4; ++mi)
#pragma unroll
      for (int ni = 0; ni < 4; ++ni)
        acc[mi][ni] = __builtin_amdgcn_mfma_f32_16x16x32_bf16(af[mi], bf[ni], acc[mi][ni], 0, 0, 0);
  }

#pragma unroll
  for (int mi = 0; mi < 4; ++mi)
#pragma unroll
    for (int ni = 0; ni < 4; ++ni)
#pragma unroll
      for (int rr = 0; rr < 4; ++rr)
        Cs[wm * 64 + mi * 16 + (lane >> 4) * 4 + rr][wn * 64 + ni * 16 + lr] =
            __float2bfloat16(acc[mi][ni][rr]);
  __syncthreads();

  const int orow = tid >> 1, oseg = (tid & 1) * 64;
  __hip_bfloat16* dst = xg + (size_t)(by * 128 + orow) * G4_ + bx * 128 + oseg;
#pragma unroll
  for (int c2 = 0; c2 < 8; ++c2)
    *(short8*)(dst + c2 * 8) = *(const short8*)&Cs[orow][oseg + c2 * 8];
}

// ---------------------------------------------------------------------------
// Persistent recurrent kernel. 32 blocks x 512 threads (8 waves).
// Block g owns h-cols [g*32, g*32+32) => gate cols q*1024 + g*32 + [0,32).
// Wave w = (wn = w&1, wk = w>>1): computes rows 0..31 x block-local gate cols
// [wn*64, wn*64+64) over K-slice [wk*256, (wk+1)*256). W_hh stationary in
// registers (~128 VGPR). h exchanged via LLC (agent-scope atomics, no fences);
// wave wk polls only its 8 producer flags (padded to 64B lines).
// Safety: union of all waves' polls = all 32 flags, joined at the Gs barrier
// before any h store, so hbuf[t&1] can't be overwritten while still read.
// ---------------------------------------------------------------------------
__global__ __launch_bounds__(512, 2) void lstm_rec(
    const __hip_bfloat16* __restrict__ xg, const float* __restrict__ Whh,
    const int* __restrict__ lengths, const float* __restrict__ h0,
    const float* __restrict__ c0, const float* __restrict__ bih,
    const float* __restrict__ bhh, __hip_bfloat16* hbuf,
    float* __restrict__ hstate, float* __restrict__ cstate,
    int* flags, float* __restrict__ out,
    int t0, int t1, int isfirst, int islast) {
  __shared__ float Gs[4][32][132];   // [k-slice][batch][block-local gate col]

  const int g = blockIdx.x, tid = threadIdx.x;
  const int lane = tid & 63, w = tid >> 6;
  const int wn = w & 1, wk = w >> 1;
  const int lr = lane & 15, q = lane >> 4, kq = q * 8;
  const int kkb = wk * 8;                 // kk range [kkb, kkb+8), k = kk*32+kq+e

  // --- W_hh fragments -> registers (stationary). wf[ni][kk2]:
  // block-local gate col n = wn*64 + ni*16 + lr; global row = (n>>5)*H + g*32 + (n&31)
  short8 wf[4][8];
#pragma unroll
  for (int ni = 0; ni < 4; ++ni) {
    const int n = wn * 64 + ni * 16 + lr;
    const int gcol = (n >> 5) * H_ + g * JPB + (n & 31);
    const float* wbase = Whh + (size_t)gcol * H_ + kq;
#pragma unroll
    for (int kk2 = 0; kk2 < 8; ++kk2) {
      const int k0 = (kkb + kk2) * 32;
      f32x4 w0 = *(const f32x4*)(wbase + k0);
      f32x4 w1 = *(const f32x4*)(wbase + k0 + 4);
      __hip_bfloat16 tw[8];
#pragma unroll
      for (int e = 0; e < 4; ++e) { tw[e] = __float2bfloat16(w0[e]); tw[4 + e] = __float2bfloat16(w1[e]); }
      wf[ni][kk2] = *(const short8*)&tw[0];
    }
  }

  // nonlinearity ownership: all 512 threads, each owns (batch bb2, 2 cols)
  const int bb2 = tid >> 4, j2 = (tid & 15) * 2;
  const int jglob = g * JPB + j2;
  const int len_b = lengths[bb2];
  int maxlen = 0;
  for (int p = 0; p < B_; ++p) maxlen = max(maxlen, lengths[p]);
  const int tend = min(t1, maxlen);

  float hreg[2], creg[2], bias[4][2];
  if (isfirst) {
#pragma unroll
    for (int e = 0; e < 2; ++e) { hreg[e] = h0[bb2 * H_ + jglob + e]; creg[e] = c0[bb2 * H_ + jglob + e]; }
  } else {
#pragma unroll
    for (int e = 0; e < 2; ++e) { hreg[e] = hstate[bb2 * H_ + jglob + e]; creg[e] = cstate[bb2 * H_ + jglob + e]; }
  }
#pragma unroll
  for (int p = 0; p < 4; ++p)
#pragma unroll
    for (int e = 0; e < 2; ++e)
      bias[p][e] = bih[p * H_ + jglob + e] + bhh[p * H_ + jglob + e];

  unsigned int* hbuf32 = (unsigned int*)hbuf;
  const int pidx = (wk * 8 + (lane & 7)) * FSTRIDE;   // this wave's 8 producers

  for (int t = t0; t < tend; ++t) {
    // ---- xg loads: independent of h -> issue before the poll ----
    unsigned int xp[4];
    {
      const __hip_bfloat16* xgrow = xg + ((size_t)(t - t0) * B_ + bb2) * G4_ + jglob;
#pragma unroll
      for (int p = 0; p < 4; ++p) xp[p] = *(const unsigned int*)(xgrow + p * H_);
    }

    // ---- per-wave poll: wait for THIS wave's 8 k-slice producers ----
    while (true) {
      int f = __hip_atomic_load(&flags[pidx], __ATOMIC_RELAXED, __HIP_MEMORY_SCOPE_AGENT);
      if (__all((lane >= 8) || (f >= t))) break;
      __builtin_amdgcn_s_sleep(1);
    }

    // ---- A-fragments straight from hbuf (LLC-coherent u64 loads) ----
    const __hip_bfloat16* hb = hbuf + (size_t)(t & 1) * (B_ * H_);
    short8 af[2][8];
#pragma unroll
    for (int mi = 0; mi < 2; ++mi) {
      const int row = mi * 16 + lr;
#pragma unroll
      for (int kk2 = 0; kk2 < 8; ++kk2) {
        const unsigned long long* p =
            (const unsigned long long*)(hb + (size_t)row * H_ + (kkb + kk2) * 32 + kq);
        unsigned long long lo = __hip_atomic_load(p,     __ATOMIC_RELAXED, __HIP_MEMORY_SCOPE_AGENT);
        unsigned long long hi = __hip_atomic_load(p + 1, __ATOMIC_RELAXED, __HIP_MEMORY_SCOPE_AGENT);
        union { unsigned long long u[2]; short8 s; } cv;
        cv.u[0] = lo; cv.u[1] = hi;
        af[mi][kk2] = cv.s;
      }
    }

    // ---- MFMA: 32 x 64 tile over this wave's K=256 slice ----
    f32x4 acc[2][4];
#pragma unroll
    for (int mi = 0; mi < 2; ++mi)
#pragma unroll
      for (int ni = 0; ni < 4; ++ni) acc[mi][ni] = (f32x4){0.f, 0.f, 0.f, 0.f};
#pragma unroll
    for (int kk2 = 0; kk2 < 8; ++kk2)
#pragma unroll
      for (int mi = 0; mi < 2; ++mi)
#pragma unroll
        for (int ni = 0; ni < 4; ++ni)
          acc[mi][ni] = __builtin_amdgcn_mfma_f32_16x16x32_bf16(af[mi][kk2], wf[ni][kk2], acc[mi][ni], 0, 0, 0);

    // ---- write partials ----
#pragma unroll
    for (int mi = 0; mi < 2; ++mi)
#pragma unroll
      for (int ni = 0; ni < 4; ++ni)
#pragma unroll
        for (int rr = 0; rr < 4; ++rr)
          Gs[wk][mi * 16 + q * 4 + rr][wn * 64 + ni * 16 + lr] = acc[mi][ni][rr];
    __syncthreads();

    // ---- nonlinearity: thread owns (bb2, jglob..jglob+1) ----
    {
      const int upd = (t < len_b);
#pragma unroll
      for (int e = 0; e < 2; ++e) {
        const int cb = j2 + e;
        const float s0 = (Gs[0][bb2][cb]      + Gs[1][bb2][cb])      + (Gs[2][bb2][cb]      + Gs[3][bb2][cb]);
        const float s1 = (Gs[0][bb2][32 + cb] + Gs[1][bb2][32 + cb]) + (Gs[2][bb2][32 + cb] + Gs[3][bb2][32 + cb]);
        const float s2 = (Gs[0][bb2][64 + cb] + Gs[1][bb2][64 + cb]) + (Gs[2][bb2][64 + cb] + Gs[3][bb2][64 + cb]);
        const float s3 = (Gs[0][bb2][96 + cb] + Gs[1][bb2][96 + cb]) + (Gs[2][bb2][96 + cb] + Gs[3][bb2][96 + cb]);
        const float g0 = s0 + bf16bits_to_f((unsigned short)(xp[0] >> (16 * e))) + bias[0][e];
        const float g1 = s1 + bf16bits_to_f((unsigned short)(xp[1] >> (16 * e))) + bias[1][e];
        const float g2 = s2 + bf16bits_to_f((unsigned short)(xp[2] >> (16 * e))) + bias[2][e];
        const float g3 = s3 + bf16bits_to_f((unsigned short)(xp[3] >> (16 * e))) + bias[3][e];
        const float ig = sigmoidf_(g0), fg = sigmoidf_(g1);
        const float gg = tanhf(g2),     og = sigmoidf_(g3);
        const float cn = fg * creg[e] + ig * gg;
        const float hn = og * tanhf(cn);
        if (upd) { creg[e] = cn; hreg[e] = hn; }
      }
      unsigned int packed = ((unsigned int)f_to_bf16bits(hreg[1]) << 16) | f_to_bf16bits(hreg[0]);
      unsigned int* hdst = hbuf32 + (((size_t)((t + 1) & 1) * (B_ * H_) + bb2 * H_ + jglob) >> 1);
      __hip_atomic_store(hdst, packed, __ATOMIC_RELAXED, __HIP_MEMORY_SCOPE_AGENT);
    }
    __syncthreads();   // drains vmcnt -> h stores at LLC before flag
    if (tid == 0)
      __hip_atomic_store(&flags[g * FSTRIDE], t + 1, __ATOMIC_RELAXED, __HIP_MEMORY_SCOPE_AGENT);
  }

  if (islast) {
#pragma unroll
    for (int e = 0; e < 2; ++e) {
      out[bb2 * H_ + jglob + e] = hreg[e];
      out[B_ * H_ + bb2 * H_ + jglob + e] = creg[e];
    }
  } else {
#pragma unroll
    for (int e = 0; e < 2; ++e) {
      hstate[bb2 * H_ + jglob + e] = hreg[e];
      cstate[bb2 * H_ + jglob + e] = creg[e];
    }
  }
}

// init: h0 -> hbuf[0] (bf16), zero flags. Re-runs every launch (graph replay safe).
__global__ void init_k(const float* __restrict__ h0, __hip_bfloat16* __restrict__ hbuf,
                       int* __restrict__ flags) {
  int i = blockIdx.x * 256 + threadIdx.x;
  if (i < B_ * H_) hbuf[i] = __float2bfloat16(h0[i]);
  if (i < NBLK * FSTRIDE) flags[i] = 0;
}

extern "C" void kernel_launch(void* const* d_in, const int* in_sizes, int n_in,
                              void* d_out, int out_size, void* d_ws, size_t ws_size,
                              hipStream_t stream) {
  const float* x       = (const float*)d_in[0];
  const int*   lengths = (const int*)d_in[1];
  const float* h0      = (const float*)d_in[2];
  const float* c0      = (const float*)d_in[3];
  const float* Wih     = (const float*)d_in[4];
  const float* Whh     = (const float*)d_in[5];
  const float* bih     = (const float*)d_in[6];
  const float* bhh     = (const float*)d_in[7];
  float* out = (float*)d_out;

  char* ws = (char*)d_ws;
  int* flags               = (int*)ws;                               // 2 KB (padded)
  __hip_bfloat16* hbuf     = (__hip_bfloat16*)(ws + 4096);           // 2 x 64 KB
  float* hstate            = (float*)(ws + 4096 + 131072);           // 128 KB
  float* cstate            = (float*)(ws + 4096 + 262144);           // 128 KB
  __hip_bfloat16* xg       = (__hip_bfloat16*)(ws + 524288);

  size_t avail = (ws_size > 524288) ? ws_size - 524288 : 0;
  int tc = (int)(avail / ((size_t)B_ * G4_ * 2));
  if (tc > T_) tc = T_;
  tc &= ~3;               // M tile needs tc multiple of 4
  if (tc < 4) tc = 4;     // minimal chunk (assumes ws_size >= ~1.6 MB)

  hipLaunchKernelGGL(init_k, dim3(128), dim3(256), 0, stream, h0, hbuf, flags);
  for (int t0 = 0; t0 < T_; t0 += tc) {
    int len = min(tc, T_ - t0);
    dim3 gg(G4_ / 128, (len * B_) / 128);
    hipLaunchKernelGGL(xw_gemm, gg, dim3(256), 0, stream, x, Wih, xg, t0);
    hipLaunchKernelGGL(lstm_rec, dim3(NBLK), dim3(512), 0, stream,
                       xg, Whh, lengths, h0, c0, bih, bhh, hbuf, hstate, cstate,
                       flags, out, t0, t0 + len, (t0 == 0) ? 1 : 0,
                       (t0 + len >= T_) ? 1 : 0);
  }
}